// Round 11
// baseline (332.419 us; speedup 1.0000x reference)
//
#include <hip/hip_runtime.h>
#include <cstdint>
#include <cstddef>

#define C_DIM 256
#define N_PIX 10000
#define B_SZ 16

// ---------------- k_prep (R10-exact): wpe (0..59) + tiled weight transpose (60..155) ----
__global__ __launch_bounds__(256) void k_prep(
    const float* __restrict__ pe,
    const float* __restrict__ Wc, const float* __restrict__ Wb,
    const float* __restrict__ dW1, const float* __restrict__ dW2, const float* __restrict__ dW3,
    const float* __restrict__ rW1, const float* __restrict__ rW2, const float* __restrict__ rW3,
    float* __restrict__ wpe, float* __restrict__ wT) {
  __shared__ float tile[64][65];
  int tid = threadIdx.x;
  int bid = blockIdx.x;
  if (bid < 60) {
    int o = bid / 10;
    int p = (bid % 10) * 256 + tid;
    if (p >= 2500) return;
    const float* W = (o < 2) ? (Wc + o * C_DIM) : (Wb + (o - 2) * C_DIM);
    float acc = 0.f;
#pragma unroll 8
    for (int c = 0; c < C_DIM; ++c) acc = fmaf(W[c], pe[c * 2500 + p], acc);
    wpe[o * 2500 + p] = acc;
    return;
  }
  int t = bid - 60;
  int m = t >> 4;
  int tl = t & 15;
  int ty = tl >> 2, tx = tl & 3;
  const float* W;
  switch (m) {
    case 0: W = dW1; break;
    case 1: W = dW2; break;
    case 2: W = dW3; break;
    case 3: W = rW1; break;
    case 4: W = rW2; break;
    default: W = rW3; break;
  }
  int lane = tid & 63, rg = tid >> 6;
  for (int rr = rg; rr < 64; rr += 4)
    tile[rr][lane] = W[(size_t)(ty * 64 + rr) * 256 + tx * 64 + lane];
  __syncthreads();
  for (int rr = rg; rr < 64; rr += 4)
    wT[(size_t)m * 65536 + (size_t)(tx * 64 + rr) * 256 + ty * 64 + lane] = tile[lane][rr];
}

// ---------------- k_heads2 (R10-exact) --------------------------------------------------
__global__ __launch_bounds__(256, 4) void k_heads2(
    const float* __restrict__ x, const float* __restrict__ wpe,
    const float* __restrict__ Wc, const float* __restrict__ bc,
    const float* __restrict__ Wb, const float* __restrict__ bb,
    float* __restrict__ cls, float* __restrict__ bbox, float* __restrict__ conf) {
  int tid = threadIdx.x;
  int b = blockIdx.y;
  int n = blockIdx.x * 256 + tid;
  if (n >= N_PIX) return;
  const float* xb = x + (size_t)b * C_DIM * N_PIX + n;
  const float* w1p = Wc + C_DIM;
  const float* w2p = Wb;
  const float* w3p = Wb + C_DIM;
  const float* w4p = Wb + 2 * C_DIM;
  const float* w5p = Wb + 3 * C_DIM;
  float a0 = 0.f, a1 = 0.f, a2 = 0.f, a3 = 0.f, a4 = 0.f, a5 = 0.f;
  for (int c = 0; c < C_DIM; c += 8) {
    float xv0 = xb[(size_t)(c + 0) * N_PIX];
    float xv1 = xb[(size_t)(c + 1) * N_PIX];
    float xv2 = xb[(size_t)(c + 2) * N_PIX];
    float xv3 = xb[(size_t)(c + 3) * N_PIX];
    float xv4 = xb[(size_t)(c + 4) * N_PIX];
    float xv5 = xb[(size_t)(c + 5) * N_PIX];
    float xv6 = xb[(size_t)(c + 6) * N_PIX];
    float xv7 = xb[(size_t)(c + 7) * N_PIX];
#pragma unroll
    for (int j = 0; j < 8; ++j) {
      float xv = (j == 0) ? xv0 : (j == 1) ? xv1 : (j == 2) ? xv2 : (j == 3) ? xv3
               : (j == 4) ? xv4 : (j == 5) ? xv5 : (j == 6) ? xv6 : xv7;
      a0 = fmaf(Wc[c + j],  xv, a0);
      a1 = fmaf(w1p[c + j], xv, a1);
      a2 = fmaf(w2p[c + j], xv, a2);
      a3 = fmaf(w3p[c + j], xv, a3);
      a4 = fmaf(w4p[c + j], xv, a4);
      a5 = fmaf(w5p[c + j], xv, a5);
    }
  }
  int y = n / 100, xq = n % 100;
  float sy = fminf(fmaxf((y + 0.5f) * 0.5f - 0.5f, 0.0f), 49.0f);
  float sx = fminf(fmaxf((xq + 0.5f) * 0.5f - 0.5f, 0.0f), 49.0f);
  int y0 = (int)floorf(sy); int y1 = min(y0 + 1, 49); float ty = sy - (float)y0;
  int x0i = (int)floorf(sx); int x1i = min(x0i + 1, 49); float tx = sx - (float)x0i;
  float pd[6];
#pragma unroll
  for (int o = 0; o < 6; ++o) {
    const float* m = wpe + o * 2500;
    float v00 = m[y0 * 50 + x0i], v01 = m[y0 * 50 + x1i];
    float v10 = m[y1 * 50 + x0i], v11 = m[y1 * 50 + x1i];
    float r0 = v00 * (1.0f - ty) + v10 * ty;
    float r1 = v01 * (1.0f - ty) + v11 * ty;
    pd[o] = r0 * (1.0f - tx) + r1 * tx;
  }
  float c0 = a0 + pd[0] + bc[0];
  float c1 = a1 + pd[1] + bc[1];
  float b0 = a2 + pd[2] + bb[0];
  float b1 = a3 + pd[3] + bb[1];
  float b2 = a4 + pd[4] + bb[2];
  float b3 = a5 + pd[5] + bb[3];
  size_t nb = (size_t)b * N_PIX + n;
  float2 cv; cv.x = c0; cv.y = c1;
  *(float2*)(cls + nb * 2) = cv;
  float4 bv; bv.x = b0; bv.y = b1; bv.z = b2; bv.w = b3;
  *(float4*)(bbox + nb * 4) = bv;
  float m0 = fmaxf(c0, c1);
  float e0 = expf(c0 - m0), e1 = expf(c1 - m0);
  conf[nb] = e1 / (e0 + e1);
}

// ---------------- per-batch top-100 (R10-exact) -----------------------------------------
__global__ __launch_bounds__(1024) void k_topk(const float* __restrict__ conf,
                                               int* __restrict__ idx_out) {
  __shared__ unsigned int ord[N_PIX];
  __shared__ unsigned int whist[16][256];
  __shared__ unsigned int hist[256];
  __shared__ unsigned long long cand[512];
  __shared__ unsigned int s_cnt, s_prefix, s_ncand;
  int tid = threadIdx.x;
  int wv = tid >> 6;
  int b = blockIdx.x;
  const float* cb = conf + (size_t)b * N_PIX;
  for (int i = tid; i < N_PIX; i += 1024) {
    unsigned int u = __float_as_uint(cb[i]);
    ord[i] = (u & 0x80000000u) ? ~u : (u | 0x80000000u);
  }
  unsigned int prefix = 0, cnt_gt = 0;
  for (int pass = 0; pass < 4; ++pass) {
    int sh = 24 - 8 * pass;
    for (int i = tid; i < 16 * 256; i += 1024) ((unsigned int*)whist)[i] = 0;
    __syncthreads();
    unsigned int himask = (pass == 0) ? 0u : (0xFFFFFFFFu << (sh + 8));
    for (int i = tid; i < N_PIX; i += 1024) {
      unsigned int o = ord[i];
      if ((o & himask) == prefix) atomicAdd(&whist[wv][(o >> sh) & 255u], 1u);
    }
    __syncthreads();
    if (tid < 256) {
      unsigned int s = 0;
#pragma unroll
      for (int w2 = 0; w2 < 16; ++w2) s += whist[w2][tid];
      hist[tid] = s;
    }
    __syncthreads();
    if (tid == 0) {
      unsigned int c = cnt_gt; int v = 255;
      while (v > 0 && c + hist[v] < 100u) { c += hist[v]; --v; }
      s_cnt = c; s_prefix = prefix | ((unsigned int)v << sh);
    }
    __syncthreads();
    cnt_gt = s_cnt; prefix = s_prefix;
    __syncthreads();
  }
  if (tid == 0) s_ncand = 0;
  __syncthreads();
  unsigned int T = prefix;
  for (int i = tid; i < N_PIX; i += 1024) {
    unsigned int o = ord[i];
    if (o >= T) {
      unsigned int k = atomicAdd(&s_ncand, 1u);
      if (k < 512u)
        cand[k] = ((unsigned long long)o << 32) |
                  (unsigned long long)(0xFFFFFFFFu - (unsigned int)i);
    }
  }
  __syncthreads();
  unsigned int nc = s_ncand > 512u ? 512u : s_ncand;
  for (int i = tid; i < 512; i += 1024)
    if ((unsigned int)i >= nc) cand[i] = 0ull;
  __syncthreads();
  for (unsigned int k = 2; k <= 512; k <<= 1) {
    for (unsigned int j = k >> 1; j > 0; j >>= 1) {
      if (tid < 512) {
        unsigned int i = (unsigned int)tid, ixj = i ^ j;
        if (ixj > i) {
          unsigned long long a = cand[i], c2 = cand[ixj];
          bool up = ((i & k) == 0);
          if ((a > c2) == up) { cand[i] = c2; cand[ixj] = a; }
        }
      }
      __syncthreads();
    }
  }
  if (tid < 100) {
    unsigned long long key = cand[511 - tid];
    idx_out[b * 100 + tid] = (int)(0xFFFFFFFFu - (unsigned int)(key & 0xFFFFFFFFull));
  }
}

// ---------------- k_mlp5 (R10-exact) ----------------------------------------------------
#define R4 4

__device__ __forceinline__ float pos_bilinear(const float* __restrict__ pe, int c, int n) {
  int y = n / 100, xq = n % 100;
  float sy = fminf(fmaxf((y + 0.5f) * 0.5f - 0.5f, 0.0f), 49.0f);
  float sx = fminf(fmaxf((xq + 0.5f) * 0.5f - 0.5f, 0.0f), 49.0f);
  int y0 = (int)floorf(sy); int y1 = min(y0 + 1, 49); float ty = sy - (float)y0;
  int x0i = (int)floorf(sx); int x1i = min(x0i + 1, 49); float tx = sx - (float)x0i;
  const float* p = pe + (size_t)c * 2500;
  float v00 = p[y0 * 50 + x0i], v01 = p[y0 * 50 + x1i];
  float v10 = p[y1 * 50 + x0i], v11 = p[y1 * 50 + x1i];
  float rr0 = v00 * (1.0f - ty) + v10 * ty;
  float rr1 = v01 * (1.0f - ty) + v11 * ty;
  return rr0 * (1.0f - tx) + rr1 * tx;
}

__device__ __forceinline__ void mlp_layer_cs(const float (*in)[C_DIM], float (*outb)[C_DIM],
    float (*red)[R4][C_DIM], const float* __restrict__ Wl, const float* __restrict__ bias,
    bool relu, int og, int rg, int tid) {
  float4 acc[R4];
#pragma unroll
  for (int r = 0; r < R4; ++r) { acc[r].x = 0.f; acc[r].y = 0.f; acc[r].z = 0.f; acc[r].w = 0.f; }
  int c0 = rg * 64;
#pragma unroll 4
  for (int ci = 0; ci < 64; ci += 4) {
    int c = c0 + ci;
    float4 w0 = *(const float4*)(Wl + (size_t)(c + 0) * C_DIM + og * 4);
    float4 w1 = *(const float4*)(Wl + (size_t)(c + 1) * C_DIM + og * 4);
    float4 w2 = *(const float4*)(Wl + (size_t)(c + 2) * C_DIM + og * 4);
    float4 w3 = *(const float4*)(Wl + (size_t)(c + 3) * C_DIM + og * 4);
#pragma unroll
    for (int r = 0; r < R4; ++r) {
      float4 iv = *(const float4*)(&in[r][c]);
      acc[r].x = fmaf(w0.x, iv.x, acc[r].x); acc[r].y = fmaf(w0.y, iv.x, acc[r].y);
      acc[r].z = fmaf(w0.z, iv.x, acc[r].z); acc[r].w = fmaf(w0.w, iv.x, acc[r].w);
      acc[r].x = fmaf(w1.x, iv.y, acc[r].x); acc[r].y = fmaf(w1.y, iv.y, acc[r].y);
      acc[r].z = fmaf(w1.z, iv.y, acc[r].z); acc[r].w = fmaf(w1.w, iv.y, acc[r].w);
      acc[r].x = fmaf(w2.x, iv.z, acc[r].x); acc[r].y = fmaf(w2.y, iv.z, acc[r].y);
      acc[r].z = fmaf(w2.z, iv.z, acc[r].z); acc[r].w = fmaf(w2.w, iv.z, acc[r].w);
      acc[r].x = fmaf(w3.x, iv.w, acc[r].x); acc[r].y = fmaf(w3.y, iv.w, acc[r].y);
      acc[r].z = fmaf(w3.z, iv.w, acc[r].z); acc[r].w = fmaf(w3.w, iv.w, acc[r].w);
    }
  }
#pragma unroll
  for (int r = 0; r < R4; ++r) *(float4*)(&red[rg][r][og * 4]) = acc[r];
  __syncthreads();
#pragma unroll
  for (int r = 0; r < R4; ++r) {
    float s = red[0][r][tid] + red[1][r][tid] + red[2][r][tid] + red[3][r][tid] + bias[tid];
    outb[r][tid] = relu ? fmaxf(s, 0.f) : s;
  }
  __syncthreads();
}

__global__ __launch_bounds__(256, 2) void k_mlp5(
    const float* __restrict__ x, const float* __restrict__ pe, const int* __restrict__ idx,
    const float* __restrict__ wT,
    const float* __restrict__ db1, const float* __restrict__ db2, const float* __restrict__ db3,
    const float* __restrict__ rb1, const float* __restrict__ rb2, const float* __restrict__ rb3,
    const float* __restrict__ det_q, const float* __restrict__ rec_q,
    float* __restrict__ det, float* __restrict__ rec) {
  __shared__ float actA[R4][C_DIM];
  __shared__ float actB[R4][C_DIM];
  __shared__ float red[4][R4][C_DIM];
  int tid = threadIdx.x;
  int og = tid & 63, rg = tid >> 6;
  int base = blockIdx.x * R4;
  bool is_det = base < 1600;
  const float *W1, *W2, *W3, *B1, *B2, *B3;
  if (is_det) {
    W1 = wT;          W2 = wT + 65536;  W3 = wT + 131072;
    B1 = db1; B2 = db2; B3 = db3;
  } else {
    W1 = wT + 196608; W2 = wT + 262144; W3 = wT + 327680;
    B1 = rb1; B2 = rb2; B3 = rb3;
  }
#pragma unroll
  for (int lr = 0; lr < R4; ++lr) {
    int rowid = base + lr;
    int b, r;
    if (rowid < 1600) { b = rowid / 100; r = rowid % 100; }
    else { int t2 = rowid - 1600; b = t2 / 25; r = t2 % 25; }
    int n = idx[b * 100 + r];
    actA[lr][tid] = x[((size_t)b * C_DIM + tid) * N_PIX + n] + pos_bilinear(pe, tid, n);
  }
  __syncthreads();
  mlp_layer_cs(actA, actB, red, W1, B1, true,  og, rg, tid);
  mlp_layer_cs(actB, actA, red, W2, B2, true,  og, rg, tid);
  mlp_layer_cs(actA, actB, red, W3, B3, false, og, rg, tid);
#pragma unroll
  for (int lr = 0; lr < R4; ++lr) {
    int rowid = base + lr;
    if (rowid < 1600) {
      int r = rowid % 100;
      det[(size_t)rowid * C_DIM + tid] = actB[lr][tid] + det_q[r * C_DIM + tid];
    } else {
      int t2 = rowid - 1600; int r = t2 % 25;
      rec[(size_t)t2 * C_DIM + tid] = actB[lr][tid] + rec_q[r * C_DIM + tid];
    }
  }
}

extern "C" void kernel_launch(void* const* d_in, const int* in_sizes, int n_in,
                              void* d_out, int out_size, void* d_ws, size_t ws_size,
                              hipStream_t stream) {
  const float* x     = (const float*)d_in[0];
  const float* Wc    = (const float*)d_in[1];
  const float* bc    = (const float*)d_in[2];
  const float* Wb    = (const float*)d_in[3];
  const float* bb    = (const float*)d_in[4];
  const float* dW1   = (const float*)d_in[5];
  const float* db1   = (const float*)d_in[6];
  const float* dW2   = (const float*)d_in[7];
  const float* db2   = (const float*)d_in[8];
  const float* dW3   = (const float*)d_in[9];
  const float* db3   = (const float*)d_in[10];
  const float* rW1   = (const float*)d_in[11];
  const float* rb1   = (const float*)d_in[12];
  const float* rW2   = (const float*)d_in[13];
  const float* rb2   = (const float*)d_in[14];
  const float* rW3   = (const float*)d_in[15];
  const float* rb3   = (const float*)d_in[16];
  const float* det_q = (const float*)d_in[17];
  const float* rec_q = (const float*)d_in[18];
  const float* pos_e = (const float*)d_in[19];

  float* out  = (float*)d_out;
  float* det  = out;                // [16,100,256]
  float* rec  = out + 409600;       // [16, 25,256]
  float* cls  = out + 512000;       // [16,10000,2]
  float* bbox = out + 832000;       // [16,10000,4]

  // ws layout (bytes): wT @0 (1572864) | conf @1572864 (640000) | idx @2212864 | wpe @2221056
  char* wsb = (char*)d_ws;
  float* wT   = (float*)wsb;
  float* conf = (float*)(wsb + 1572864);
  int*   idx  = (int*)(wsb + 2212864);
  float* wpe  = (float*)(wsb + 2221056);

  k_prep<<<156, 256, 0, stream>>>(pos_e, Wc, Wb, dW1, dW2, dW3, rW1, rW2, rW3, wpe, wT);
  k_heads2<<<dim3(40, B_SZ), 256, 0, stream>>>(x, wpe, Wc, bc, Wb, bb, cls, bbox, conf);
  k_topk<<<B_SZ, 1024, 0, stream>>>(conf, idx);
  // MEASUREMENT: k_mlp5 launched 6x (idempotent). mlp5_warm = (total - 135.7)/5.
  for (int rep = 0; rep < 6; ++rep) {
    k_mlp5<<<500, 256, 0, stream>>>(x, pos_e, idx, wT,
                                    db1, db2, db3, rb1, rb2, rb3,
                                    det_q, rec_q, det, rec);
  }
}

// Round 12
// 263.788 us; speedup vs baseline: 1.2602x; 1.2602x over previous
//
#include <hip/hip_runtime.h>
#include <cstdint>
#include <cstddef>

#define C_DIM 256
#define N_PIX 10000
#define B_SZ 16

// ---------------- k_prep (R10-exact): wpe (0..59) + tiled weight transpose (60..155) ----
__global__ __launch_bounds__(256) void k_prep(
    const float* __restrict__ pe,
    const float* __restrict__ Wc, const float* __restrict__ Wb,
    const float* __restrict__ dW1, const float* __restrict__ dW2, const float* __restrict__ dW3,
    const float* __restrict__ rW1, const float* __restrict__ rW2, const float* __restrict__ rW3,
    float* __restrict__ wpe, float* __restrict__ wT) {
  __shared__ float tile[64][65];
  int tid = threadIdx.x;
  int bid = blockIdx.x;
  if (bid < 60) {
    int o = bid / 10;
    int p = (bid % 10) * 256 + tid;
    if (p >= 2500) return;
    const float* W = (o < 2) ? (Wc + o * C_DIM) : (Wb + (o - 2) * C_DIM);
    float acc = 0.f;
#pragma unroll 8
    for (int c = 0; c < C_DIM; ++c) acc = fmaf(W[c], pe[c * 2500 + p], acc);
    wpe[o * 2500 + p] = acc;
    return;
  }
  int t = bid - 60;
  int m = t >> 4;
  int tl = t & 15;
  int ty = tl >> 2, tx = tl & 3;
  const float* W;
  switch (m) {
    case 0: W = dW1; break;
    case 1: W = dW2; break;
    case 2: W = dW3; break;
    case 3: W = rW1; break;
    case 4: W = rW2; break;
    default: W = rW3; break;
  }
  int lane = tid & 63, rg = tid >> 6;
  for (int rr = rg; rr < 64; rr += 4)
    tile[rr][lane] = W[(size_t)(ty * 64 + rr) * 256 + tx * 64 + lane];
  __syncthreads();
  for (int rr = rg; rr < 64; rr += 4)
    wT[(size_t)m * 65536 + (size_t)(tx * 64 + rr) * 256 + ty * 64 + lane] = tile[lane][rr];
}

// ---------------- k_heads4: 16 loads in flight (4KB/wave), same math order --------------
__global__ __launch_bounds__(256, 4) void k_heads4(
    const float* __restrict__ x, const float* __restrict__ wpe,
    const float* __restrict__ Wc, const float* __restrict__ bc,
    const float* __restrict__ Wb, const float* __restrict__ bb,
    float* __restrict__ cls, float* __restrict__ bbox, float* __restrict__ conf) {
  int tid = threadIdx.x;
  int b = blockIdx.y;
  int n = blockIdx.x * 256 + tid;            // grid (40, 16)
  if (n >= N_PIX) return;
  const float* xb = x + (size_t)b * C_DIM * N_PIX + n;
  const float* w1p = Wc + C_DIM;
  const float* w2p = Wb;
  const float* w3p = Wb + C_DIM;
  const float* w4p = Wb + 2 * C_DIM;
  const float* w5p = Wb + 3 * C_DIM;
  float a0 = 0.f, a1 = 0.f, a2 = 0.f, a3 = 0.f, a4 = 0.f, a5 = 0.f;
  for (int c = 0; c < C_DIM; c += 16) {
    float xv[16];
#pragma unroll
    for (int j = 0; j < 16; ++j) xv[j] = xb[(size_t)(c + j) * N_PIX];
#pragma unroll
    for (int j = 0; j < 16; ++j) {
      float v = xv[j];
      a0 = fmaf(Wc[c + j],  v, a0);
      a1 = fmaf(w1p[c + j], v, a1);
      a2 = fmaf(w2p[c + j], v, a2);
      a3 = fmaf(w3p[c + j], v, a3);
      a4 = fmaf(w4p[c + j], v, a4);
      a5 = fmaf(w5p[c + j], v, a5);
    }
  }
  int y = n / 100, xq = n % 100;
  float sy = fminf(fmaxf((y + 0.5f) * 0.5f - 0.5f, 0.0f), 49.0f);
  float sx = fminf(fmaxf((xq + 0.5f) * 0.5f - 0.5f, 0.0f), 49.0f);
  int y0 = (int)floorf(sy); int y1 = min(y0 + 1, 49); float ty = sy - (float)y0;
  int x0i = (int)floorf(sx); int x1i = min(x0i + 1, 49); float tx = sx - (float)x0i;
  float pd[6];
#pragma unroll
  for (int o = 0; o < 6; ++o) {
    const float* m = wpe + o * 2500;
    float v00 = m[y0 * 50 + x0i], v01 = m[y0 * 50 + x1i];
    float v10 = m[y1 * 50 + x0i], v11 = m[y1 * 50 + x1i];
    float r0 = v00 * (1.0f - ty) + v10 * ty;
    float r1 = v01 * (1.0f - ty) + v11 * ty;
    pd[o] = r0 * (1.0f - tx) + r1 * tx;
  }
  float c0 = a0 + pd[0] + bc[0];
  float c1 = a1 + pd[1] + bc[1];
  float b0 = a2 + pd[2] + bb[0];
  float b1 = a3 + pd[3] + bb[1];
  float b2 = a4 + pd[4] + bb[2];
  float b3 = a5 + pd[5] + bb[3];
  size_t nb = (size_t)b * N_PIX + n;
  float2 cv; cv.x = c0; cv.y = c1;
  *(float2*)(cls + nb * 2) = cv;
  float4 bv; bv.x = b0; bv.y = b1; bv.z = b2; bv.w = b3;
  *(float4*)(bbox + nb * 4) = bv;
  float m0 = fmaxf(c0, c1);
  float e0 = expf(c0 - m0), e1 = expf(c1 - m0);
  conf[nb] = e1 / (e0 + e1);
}

// ---------------- per-batch top-100 (R10-exact) -----------------------------------------
__global__ __launch_bounds__(1024) void k_topk(const float* __restrict__ conf,
                                               int* __restrict__ idx_out) {
  __shared__ unsigned int ord[N_PIX];
  __shared__ unsigned int whist[16][256];
  __shared__ unsigned int hist[256];
  __shared__ unsigned long long cand[512];
  __shared__ unsigned int s_cnt, s_prefix, s_ncand;
  int tid = threadIdx.x;
  int wv = tid >> 6;
  int b = blockIdx.x;
  const float* cb = conf + (size_t)b * N_PIX;
  for (int i = tid; i < N_PIX; i += 1024) {
    unsigned int u = __float_as_uint(cb[i]);
    ord[i] = (u & 0x80000000u) ? ~u : (u | 0x80000000u);
  }
  unsigned int prefix = 0, cnt_gt = 0;
  for (int pass = 0; pass < 4; ++pass) {
    int sh = 24 - 8 * pass;
    for (int i = tid; i < 16 * 256; i += 1024) ((unsigned int*)whist)[i] = 0;
    __syncthreads();
    unsigned int himask = (pass == 0) ? 0u : (0xFFFFFFFFu << (sh + 8));
    for (int i = tid; i < N_PIX; i += 1024) {
      unsigned int o = ord[i];
      if ((o & himask) == prefix) atomicAdd(&whist[wv][(o >> sh) & 255u], 1u);
    }
    __syncthreads();
    if (tid < 256) {
      unsigned int s = 0;
#pragma unroll
      for (int w2 = 0; w2 < 16; ++w2) s += whist[w2][tid];
      hist[tid] = s;
    }
    __syncthreads();
    if (tid == 0) {
      unsigned int c = cnt_gt; int v = 255;
      while (v > 0 && c + hist[v] < 100u) { c += hist[v]; --v; }
      s_cnt = c; s_prefix = prefix | ((unsigned int)v << sh);
    }
    __syncthreads();
    cnt_gt = s_cnt; prefix = s_prefix;
    __syncthreads();
  }
  if (tid == 0) s_ncand = 0;
  __syncthreads();
  unsigned int T = prefix;
  for (int i = tid; i < N_PIX; i += 1024) {
    unsigned int o = ord[i];
    if (o >= T) {
      unsigned int k = atomicAdd(&s_ncand, 1u);
      if (k < 512u)
        cand[k] = ((unsigned long long)o << 32) |
                  (unsigned long long)(0xFFFFFFFFu - (unsigned int)i);
    }
  }
  __syncthreads();
  unsigned int nc = s_ncand > 512u ? 512u : s_ncand;
  for (int i = tid; i < 512; i += 1024)
    if ((unsigned int)i >= nc) cand[i] = 0ull;
  __syncthreads();
  for (unsigned int k = 2; k <= 512; k <<= 1) {
    for (unsigned int j = k >> 1; j > 0; j >>= 1) {
      if (tid < 512) {
        unsigned int i = (unsigned int)tid, ixj = i ^ j;
        if (ixj > i) {
          unsigned long long a = cand[i], c2 = cand[ixj];
          bool up = ((i & k) == 0);
          if ((a > c2) == up) { cand[i] = c2; cand[ixj] = a; }
        }
      }
      __syncthreads();
    }
  }
  if (tid < 100) {
    unsigned long long key = cand[511 - tid];
    idx_out[b * 100 + tid] = (int)(0xFFFFFFFFu - (unsigned int)(key & 0xFFFFFFFFull));
  }
}

// ---------------- k_mlp5 (R10-exact) ----------------------------------------------------
#define R4 4

__device__ __forceinline__ float pos_bilinear(const float* __restrict__ pe, int c, int n) {
  int y = n / 100, xq = n % 100;
  float sy = fminf(fmaxf((y + 0.5f) * 0.5f - 0.5f, 0.0f), 49.0f);
  float sx = fminf(fmaxf((xq + 0.5f) * 0.5f - 0.5f, 0.0f), 49.0f);
  int y0 = (int)floorf(sy); int y1 = min(y0 + 1, 49); float ty = sy - (float)y0;
  int x0i = (int)floorf(sx); int x1i = min(x0i + 1, 49); float tx = sx - (float)x0i;
  const float* p = pe + (size_t)c * 2500;
  float v00 = p[y0 * 50 + x0i], v01 = p[y0 * 50 + x1i];
  float v10 = p[y1 * 50 + x0i], v11 = p[y1 * 50 + x1i];
  float rr0 = v00 * (1.0f - ty) + v10 * ty;
  float rr1 = v01 * (1.0f - ty) + v11 * ty;
  return rr0 * (1.0f - tx) + rr1 * tx;
}

__device__ __forceinline__ void mlp_layer_cs(const float (*in)[C_DIM], float (*outb)[C_DIM],
    float (*red)[R4][C_DIM], const float* __restrict__ Wl, const float* __restrict__ bias,
    bool relu, int og, int rg, int tid) {
  float4 acc[R4];
#pragma unroll
  for (int r = 0; r < R4; ++r) { acc[r].x = 0.f; acc[r].y = 0.f; acc[r].z = 0.f; acc[r].w = 0.f; }
  int c0 = rg * 64;
#pragma unroll 4
  for (int ci = 0; ci < 64; ci += 4) {
    int c = c0 + ci;
    float4 w0 = *(const float4*)(Wl + (size_t)(c + 0) * C_DIM + og * 4);
    float4 w1 = *(const float4*)(Wl + (size_t)(c + 1) * C_DIM + og * 4);
    float4 w2 = *(const float4*)(Wl + (size_t)(c + 2) * C_DIM + og * 4);
    float4 w3 = *(const float4*)(Wl + (size_t)(c + 3) * C_DIM + og * 4);
#pragma unroll
    for (int r = 0; r < R4; ++r) {
      float4 iv = *(const float4*)(&in[r][c]);
      acc[r].x = fmaf(w0.x, iv.x, acc[r].x); acc[r].y = fmaf(w0.y, iv.x, acc[r].y);
      acc[r].z = fmaf(w0.z, iv.x, acc[r].z); acc[r].w = fmaf(w0.w, iv.x, acc[r].w);
      acc[r].x = fmaf(w1.x, iv.y, acc[r].x); acc[r].y = fmaf(w1.y, iv.y, acc[r].y);
      acc[r].z = fmaf(w1.z, iv.y, acc[r].z); acc[r].w = fmaf(w1.w, iv.y, acc[r].w);
      acc[r].x = fmaf(w2.x, iv.z, acc[r].x); acc[r].y = fmaf(w2.y, iv.z, acc[r].y);
      acc[r].z = fmaf(w2.z, iv.z, acc[r].z); acc[r].w = fmaf(w2.w, iv.z, acc[r].w);
      acc[r].x = fmaf(w3.x, iv.w, acc[r].x); acc[r].y = fmaf(w3.y, iv.w, acc[r].y);
      acc[r].z = fmaf(w3.z, iv.w, acc[r].z); acc[r].w = fmaf(w3.w, iv.w, acc[r].w);
    }
  }
#pragma unroll
  for (int r = 0; r < R4; ++r) *(float4*)(&red[rg][r][og * 4]) = acc[r];
  __syncthreads();
#pragma unroll
  for (int r = 0; r < R4; ++r) {
    float s = red[0][r][tid] + red[1][r][tid] + red[2][r][tid] + red[3][r][tid] + bias[tid];
    outb[r][tid] = relu ? fmaxf(s, 0.f) : s;
  }
  __syncthreads();
}

__global__ __launch_bounds__(256, 2) void k_mlp5(
    const float* __restrict__ x, const float* __restrict__ pe, const int* __restrict__ idx,
    const float* __restrict__ wT,
    const float* __restrict__ db1, const float* __restrict__ db2, const float* __restrict__ db3,
    const float* __restrict__ rb1, const float* __restrict__ rb2, const float* __restrict__ rb3,
    const float* __restrict__ det_q, const float* __restrict__ rec_q,
    float* __restrict__ det, float* __restrict__ rec) {
  __shared__ float actA[R4][C_DIM];
  __shared__ float actB[R4][C_DIM];
  __shared__ float red[4][R4][C_DIM];
  int tid = threadIdx.x;
  int og = tid & 63, rg = tid >> 6;
  int base = blockIdx.x * R4;
  bool is_det = base < 1600;
  const float *W1, *W2, *W3, *B1, *B2, *B3;
  if (is_det) {
    W1 = wT;          W2 = wT + 65536;  W3 = wT + 131072;
    B1 = db1; B2 = db2; B3 = db3;
  } else {
    W1 = wT + 196608; W2 = wT + 262144; W3 = wT + 327680;
    B1 = rb1; B2 = rb2; B3 = rb3;
  }
#pragma unroll
  for (int lr = 0; lr < R4; ++lr) {
    int rowid = base + lr;
    int b, r;
    if (rowid < 1600) { b = rowid / 100; r = rowid % 100; }
    else { int t2 = rowid - 1600; b = t2 / 25; r = t2 % 25; }
    int n = idx[b * 100 + r];
    actA[lr][tid] = x[((size_t)b * C_DIM + tid) * N_PIX + n] + pos_bilinear(pe, tid, n);
  }
  __syncthreads();
  mlp_layer_cs(actA, actB, red, W1, B1, true,  og, rg, tid);
  mlp_layer_cs(actB, actA, red, W2, B2, true,  og, rg, tid);
  mlp_layer_cs(actA, actB, red, W3, B3, false, og, rg, tid);
#pragma unroll
  for (int lr = 0; lr < R4; ++lr) {
    int rowid = base + lr;
    if (rowid < 1600) {
      int r = rowid % 100;
      det[(size_t)rowid * C_DIM + tid] = actB[lr][tid] + det_q[r * C_DIM + tid];
    } else {
      int t2 = rowid - 1600; int r = t2 % 25;
      rec[(size_t)t2 * C_DIM + tid] = actB[lr][tid] + rec_q[r * C_DIM + tid];
    }
  }
}

extern "C" void kernel_launch(void* const* d_in, const int* in_sizes, int n_in,
                              void* d_out, int out_size, void* d_ws, size_t ws_size,
                              hipStream_t stream) {
  const float* x     = (const float*)d_in[0];
  const float* Wc    = (const float*)d_in[1];
  const float* bc    = (const float*)d_in[2];
  const float* Wb    = (const float*)d_in[3];
  const float* bb    = (const float*)d_in[4];
  const float* dW1   = (const float*)d_in[5];
  const float* db1   = (const float*)d_in[6];
  const float* dW2   = (const float*)d_in[7];
  const float* db2   = (const float*)d_in[8];
  const float* dW3   = (const float*)d_in[9];
  const float* db3   = (const float*)d_in[10];
  const float* rW1   = (const float*)d_in[11];
  const float* rb1   = (const float*)d_in[12];
  const float* rW2   = (const float*)d_in[13];
  const float* rb2   = (const float*)d_in[14];
  const float* rW3   = (const float*)d_in[15];
  const float* rb3   = (const float*)d_in[16];
  const float* det_q = (const float*)d_in[17];
  const float* rec_q = (const float*)d_in[18];
  const float* pos_e = (const float*)d_in[19];

  float* out  = (float*)d_out;
  float* det  = out;                // [16,100,256]
  float* rec  = out + 409600;       // [16, 25,256]
  float* cls  = out + 512000;       // [16,10000,2]
  float* bbox = out + 832000;       // [16,10000,4]

  // ws layout (bytes): wT @0 (1572864) | conf @1572864 (640000) | idx @2212864 | wpe @2221056
  char* wsb = (char*)d_ws;
  float* wT   = (float*)wsb;
  float* conf = (float*)(wsb + 1572864);
  int*   idx  = (int*)(wsb + 2212864);
  float* wpe  = (float*)(wsb + 2221056);

  k_prep<<<156, 256, 0, stream>>>(pos_e, Wc, Wb, dW1, dW2, dW3, rW1, rW2, rW3, wpe, wT);
  // MEASUREMENT: k_heads4 launched 5x (idempotent, bitwise-identical outputs).
  // heads4_warm = (T - 135.7 - (heads4_cold - heads2_cold)) / 4.
  for (int rep = 0; rep < 5; ++rep) {
    k_heads4<<<dim3(40, B_SZ), 256, 0, stream>>>(x, wpe, Wc, bc, Wb, bb, cls, bbox, conf);
  }
  k_topk<<<B_SZ, 1024, 0, stream>>>(conf, idx);
  k_mlp5<<<500, 256, 0, stream>>>(x, pos_e, idx, wT,
                                  db1, db2, db3, rb1, rb2, rb3,
                                  det_q, rec_q, det, rec);
}

// Round 13
// 145.110 us; speedup vs baseline: 2.2908x; 1.8178x over previous
//
#include <hip/hip_runtime.h>
#include <cstdint>
#include <cstddef>

#define C_DIM 256
#define N_PIX 10000
#define B_SZ 16

// ---------------- k_prep (R10-exact): wpe (0..59) + tiled weight transpose (60..155) ----
__global__ __launch_bounds__(256) void k_prep(
    const float* __restrict__ pe,
    const float* __restrict__ Wc, const float* __restrict__ Wb,
    const float* __restrict__ dW1, const float* __restrict__ dW2, const float* __restrict__ dW3,
    const float* __restrict__ rW1, const float* __restrict__ rW2, const float* __restrict__ rW3,
    float* __restrict__ wpe, float* __restrict__ wT) {
  __shared__ float tile[64][65];
  int tid = threadIdx.x;
  int bid = blockIdx.x;
  if (bid < 60) {
    int o = bid / 10;
    int p = (bid % 10) * 256 + tid;
    if (p >= 2500) return;
    const float* W = (o < 2) ? (Wc + o * C_DIM) : (Wb + (o - 2) * C_DIM);
    float acc = 0.f;
#pragma unroll 8
    for (int c = 0; c < C_DIM; ++c) acc = fmaf(W[c], pe[c * 2500 + p], acc);
    wpe[o * 2500 + p] = acc;
    return;
  }
  int t = bid - 60;
  int m = t >> 4;
  int tl = t & 15;
  int ty = tl >> 2, tx = tl & 3;
  const float* W;
  switch (m) {
    case 0: W = dW1; break;
    case 1: W = dW2; break;
    case 2: W = dW3; break;
    case 3: W = rW1; break;
    case 4: W = rW2; break;
    default: W = rW3; break;
  }
  int lane = tid & 63, rg = tid >> 6;
  for (int rr = rg; rr < 64; rr += 4)
    tile[rr][lane] = W[(size_t)(ty * 64 + rr) * 256 + tx * 64 + lane];
  __syncthreads();
  for (int rr = rg; rr < 64; rr += 4)
    wT[(size_t)m * 65536 + (size_t)(tx * 64 + rr) * 256 + ty * 64 + lane] = tile[lane][rr];
}

// ---------------- k_heads4 (R12-exact, single launch) -----------------------------------
__global__ __launch_bounds__(256, 4) void k_heads4(
    const float* __restrict__ x, const float* __restrict__ wpe,
    const float* __restrict__ Wc, const float* __restrict__ bc,
    const float* __restrict__ Wb, const float* __restrict__ bb,
    float* __restrict__ cls, float* __restrict__ bbox, float* __restrict__ conf) {
  int tid = threadIdx.x;
  int b = blockIdx.y;
  int n = blockIdx.x * 256 + tid;
  if (n >= N_PIX) return;
  const float* xb = x + (size_t)b * C_DIM * N_PIX + n;
  const float* w1p = Wc + C_DIM;
  const float* w2p = Wb;
  const float* w3p = Wb + C_DIM;
  const float* w4p = Wb + 2 * C_DIM;
  const float* w5p = Wb + 3 * C_DIM;
  float a0 = 0.f, a1 = 0.f, a2 = 0.f, a3 = 0.f, a4 = 0.f, a5 = 0.f;
  for (int c = 0; c < C_DIM; c += 16) {
    float xv[16];
#pragma unroll
    for (int j = 0; j < 16; ++j) xv[j] = xb[(size_t)(c + j) * N_PIX];
#pragma unroll
    for (int j = 0; j < 16; ++j) {
      float v = xv[j];
      a0 = fmaf(Wc[c + j],  v, a0);
      a1 = fmaf(w1p[c + j], v, a1);
      a2 = fmaf(w2p[c + j], v, a2);
      a3 = fmaf(w3p[c + j], v, a3);
      a4 = fmaf(w4p[c + j], v, a4);
      a5 = fmaf(w5p[c + j], v, a5);
    }
  }
  int y = n / 100, xq = n % 100;
  float sy = fminf(fmaxf((y + 0.5f) * 0.5f - 0.5f, 0.0f), 49.0f);
  float sx = fminf(fmaxf((xq + 0.5f) * 0.5f - 0.5f, 0.0f), 49.0f);
  int y0 = (int)floorf(sy); int y1 = min(y0 + 1, 49); float ty = sy - (float)y0;
  int x0i = (int)floorf(sx); int x1i = min(x0i + 1, 49); float tx = sx - (float)x0i;
  float pd[6];
#pragma unroll
  for (int o = 0; o < 6; ++o) {
    const float* m = wpe + o * 2500;
    float v00 = m[y0 * 50 + x0i], v01 = m[y0 * 50 + x1i];
    float v10 = m[y1 * 50 + x0i], v11 = m[y1 * 50 + x1i];
    float r0 = v00 * (1.0f - ty) + v10 * ty;
    float r1 = v01 * (1.0f - ty) + v11 * ty;
    pd[o] = r0 * (1.0f - tx) + r1 * tx;
  }
  float c0 = a0 + pd[0] + bc[0];
  float c1 = a1 + pd[1] + bc[1];
  float b0 = a2 + pd[2] + bb[0];
  float b1 = a3 + pd[3] + bb[1];
  float b2 = a4 + pd[4] + bb[2];
  float b3 = a5 + pd[5] + bb[3];
  size_t nb = (size_t)b * N_PIX + n;
  float2 cv; cv.x = c0; cv.y = c1;
  *(float2*)(cls + nb * 2) = cv;
  float4 bv; bv.x = b0; bv.y = b1; bv.z = b2; bv.w = b3;
  *(float4*)(bbox + nb * 4) = bv;
  float m0 = fmaxf(c0, c1);
  float e0 = expf(c0 - m0), e1 = expf(c1 - m0);
  conf[nb] = e1 / (e0 + e1);
}

// ---------------- k_topk: parallel suffix-scan threshold (same semantics) ---------------
__global__ __launch_bounds__(1024) void k_topk(const float* __restrict__ conf,
                                               int* __restrict__ idx_out) {
  __shared__ unsigned int ord[N_PIX];
  __shared__ unsigned int whist[16][256];
  __shared__ unsigned int hist[256];
  __shared__ unsigned int sfx[256];
  __shared__ unsigned long long cand[512];
  __shared__ unsigned int s_cnt, s_prefix, s_ncand;
  int tid = threadIdx.x;
  int wv = tid >> 6;
  int b = blockIdx.x;
  const float* cb = conf + (size_t)b * N_PIX;
  for (int i = tid; i < N_PIX; i += 1024) {
    unsigned int u = __float_as_uint(cb[i]);
    ord[i] = (u & 0x80000000u) ? ~u : (u | 0x80000000u);
  }
  unsigned int prefix = 0, cnt_gt = 0;
  for (int pass = 0; pass < 4; ++pass) {
    int sh = 24 - 8 * pass;
    for (int i = tid; i < 16 * 256; i += 1024) ((unsigned int*)whist)[i] = 0;
    __syncthreads();
    unsigned int himask = (pass == 0) ? 0u : (0xFFFFFFFFu << (sh + 8));
    for (int i = tid; i < N_PIX; i += 1024) {
      unsigned int o = ord[i];
      if ((o & himask) == prefix) atomicAdd(&whist[wv][(o >> sh) & 255u], 1u);
    }
    __syncthreads();
    if (tid < 256) {
      unsigned int s = 0;
#pragma unroll
      for (int w2 = 0; w2 < 16; ++w2) s += whist[w2][tid];
      hist[tid] = s;
    }
    __syncthreads();
    // parallel suffix sums: sfx[t] = hist[t] + ... + hist[255]
    if (tid < 256) {
      unsigned int s = 0;
      for (int u = tid; u < 256; ++u) s += hist[u];
      sfx[tid] = s;
    }
    __syncthreads();
    // v* = max{v : cnt_gt + sfx[v] >= 100}; s_cnt = cnt_gt + sfx[v*+1]
    if (tid < 256) {
      unsigned int Sv = sfx[tid];
      unsigned int Sn = (tid < 255) ? sfx[tid + 1] : 0u;
      if (cnt_gt + Sv >= 100u && (tid == 255 || cnt_gt + Sn < 100u)) {
        s_cnt = cnt_gt + Sn;
        s_prefix = prefix | ((unsigned int)tid << sh);
      }
    }
    __syncthreads();
    cnt_gt = s_cnt; prefix = s_prefix;
    __syncthreads();
  }
  if (tid == 0) s_ncand = 0;
  __syncthreads();
  unsigned int T = prefix;
  for (int i = tid; i < N_PIX; i += 1024) {
    unsigned int o = ord[i];
    if (o >= T) {
      unsigned int k = atomicAdd(&s_ncand, 1u);
      if (k < 512u)
        cand[k] = ((unsigned long long)o << 32) |
                  (unsigned long long)(0xFFFFFFFFu - (unsigned int)i);
    }
  }
  __syncthreads();
  unsigned int nc = s_ncand > 512u ? 512u : s_ncand;
  for (int i = tid; i < 512; i += 1024)
    if ((unsigned int)i >= nc) cand[i] = 0ull;
  __syncthreads();
  for (unsigned int k = 2; k <= 512; k <<= 1) {
    for (unsigned int j = k >> 1; j > 0; j >>= 1) {
      if (tid < 512) {
        unsigned int i = (unsigned int)tid, ixj = i ^ j;
        if (ixj > i) {
          unsigned long long a = cand[i], c2 = cand[ixj];
          bool up = ((i & k) == 0);
          if ((a > c2) == up) { cand[i] = c2; cand[ixj] = a; }
        }
      }
      __syncthreads();
    }
  }
  if (tid < 100) {
    unsigned long long key = cand[511 - tid];
    idx_out[b * 100 + tid] = (int)(0xFFFFFFFFu - (unsigned int)(key & 0xFFFFFFFFull));
  }
}

// ---------------- gather: act[row][c] = x[b][c][n] + pos, rows 0..1999 -------------------
__device__ __forceinline__ float pos_bilinear(const float* __restrict__ pe, int c, int n) {
  int y = n / 100, xq = n % 100;
  float sy = fminf(fmaxf((y + 0.5f) * 0.5f - 0.5f, 0.0f), 49.0f);
  float sx = fminf(fmaxf((xq + 0.5f) * 0.5f - 0.5f, 0.0f), 49.0f);
  int y0 = (int)floorf(sy); int y1 = min(y0 + 1, 49); float ty = sy - (float)y0;
  int x0i = (int)floorf(sx); int x1i = min(x0i + 1, 49); float tx = sx - (float)x0i;
  const float* p = pe + (size_t)c * 2500;
  float v00 = p[y0 * 50 + x0i], v01 = p[y0 * 50 + x1i];
  float v10 = p[y1 * 50 + x0i], v11 = p[y1 * 50 + x1i];
  float rr0 = v00 * (1.0f - ty) + v10 * ty;
  float rr1 = v01 * (1.0f - ty) + v11 * ty;
  return rr0 * (1.0f - tx) + rr1 * tx;
}

__global__ __launch_bounds__(256) void k_gather(
    const float* __restrict__ x, const float* __restrict__ pe, const int* __restrict__ idx,
    float* __restrict__ act) {
  int tid = threadIdx.x;
  int base = blockIdx.x * 8;    // 250 blocks -> rows 0..1999
  for (int lr = 0; lr < 8; ++lr) {
    int row = base + lr;
    int b, r;
    if (row < 1600) { b = row / 100; r = row % 100; }
    else { int t2 = row - 1600; b = t2 / 25; r = t2 % 25; }
    int n = idx[b * 100 + r];
    act[(size_t)row * C_DIM + tid] =
        x[((size_t)b * C_DIM + tid) * N_PIX + n] + pos_bilinear(pe, tid, n);
  }
}

// ---------------- tiled GEMM layer: out[row][o] = relu(act @ wT + bias) ------------------
// grid (32, 4): bx = 64-row tile (0..24 det, 25..31 rec), by = 64-out tile. 4x4 micro.
__global__ __launch_bounds__(256) void k_lin(
    const float* __restrict__ actin, float* __restrict__ actout,
    const float* __restrict__ wTd, const float* __restrict__ wTr,
    const float* __restrict__ bd, const float* __restrict__ br) {
  __shared__ float As[16][68];   // As[k][r] (k=c within chunk, r=row in tile), pad 68
  __shared__ float Bs[16][64];   // Bs[k][o]
  int tid = threadIdx.x;
  int bx = blockIdx.x, by = blockIdx.y;
  const float* wT   = (bx < 25) ? wTd : wTr;
  const float* bias = (bx < 25) ? bd : br;
  int rbase = bx * 64, obase = by * 64;
  int tr = tid >> 4, tc = tid & 15;
  float acc[4][4];
#pragma unroll
  for (int i = 0; i < 4; ++i)
#pragma unroll
    for (int j = 0; j < 4; ++j) acc[i][j] = 0.f;
  for (int c0 = 0; c0 < 256; c0 += 16) {
#pragma unroll
    for (int i = 0; i < 4; ++i) {
      int e = tid + i * 256;
      int r = e >> 4, k = e & 15;
      As[k][r] = actin[(size_t)(rbase + r) * 256 + c0 + k];
      int k2 = e >> 6, o = e & 63;
      Bs[k2][o] = wT[(size_t)(c0 + k2) * 256 + obase + o];
    }
    __syncthreads();
#pragma unroll
    for (int k = 0; k < 16; ++k) {
      float4 av = *(const float4*)(&As[k][tr * 4]);
      float4 bv = *(const float4*)(&Bs[k][tc * 4]);
      acc[0][0] = fmaf(av.x, bv.x, acc[0][0]); acc[0][1] = fmaf(av.x, bv.y, acc[0][1]);
      acc[0][2] = fmaf(av.x, bv.z, acc[0][2]); acc[0][3] = fmaf(av.x, bv.w, acc[0][3]);
      acc[1][0] = fmaf(av.y, bv.x, acc[1][0]); acc[1][1] = fmaf(av.y, bv.y, acc[1][1]);
      acc[1][2] = fmaf(av.y, bv.z, acc[1][2]); acc[1][3] = fmaf(av.y, bv.w, acc[1][3]);
      acc[2][0] = fmaf(av.z, bv.x, acc[2][0]); acc[2][1] = fmaf(av.z, bv.y, acc[2][1]);
      acc[2][2] = fmaf(av.z, bv.z, acc[2][2]); acc[2][3] = fmaf(av.z, bv.w, acc[2][3]);
      acc[3][0] = fmaf(av.w, bv.x, acc[3][0]); acc[3][1] = fmaf(av.w, bv.y, acc[3][1]);
      acc[3][2] = fmaf(av.w, bv.z, acc[3][2]); acc[3][3] = fmaf(av.w, bv.w, acc[3][3]);
    }
    __syncthreads();
  }
#pragma unroll
  for (int i = 0; i < 4; ++i) {
    int row = rbase + tr * 4 + i;
#pragma unroll
    for (int j = 0; j < 4; ++j) {
      int o = obase + tc * 4 + j;
      float v = acc[i][j] + bias[o];
      actout[(size_t)row * 256 + o] = fmaxf(v, 0.f);
    }
  }
}

// final layer: no relu; add query embed; scatter to det/rec (row<2000 guard)
__global__ __launch_bounds__(256) void k_lin3(
    const float* __restrict__ actin,
    const float* __restrict__ wTd, const float* __restrict__ wTr,
    const float* __restrict__ bd, const float* __restrict__ br,
    const float* __restrict__ det_q, const float* __restrict__ rec_q,
    float* __restrict__ det, float* __restrict__ rec) {
  __shared__ float As[16][68];
  __shared__ float Bs[16][64];
  int tid = threadIdx.x;
  int bx = blockIdx.x, by = blockIdx.y;
  const float* wT   = (bx < 25) ? wTd : wTr;
  const float* bias = (bx < 25) ? bd : br;
  int rbase = bx * 64, obase = by * 64;
  int tr = tid >> 4, tc = tid & 15;
  float acc[4][4];
#pragma unroll
  for (int i = 0; i < 4; ++i)
#pragma unroll
    for (int j = 0; j < 4; ++j) acc[i][j] = 0.f;
  for (int c0 = 0; c0 < 256; c0 += 16) {
#pragma unroll
    for (int i = 0; i < 4; ++i) {
      int e = tid + i * 256;
      int r = e >> 4, k = e & 15;
      As[k][r] = actin[(size_t)(rbase + r) * 256 + c0 + k];
      int k2 = e >> 6, o = e & 63;
      Bs[k2][o] = wT[(size_t)(c0 + k2) * 256 + obase + o];
    }
    __syncthreads();
#pragma unroll
    for (int k = 0; k < 16; ++k) {
      float4 av = *(const float4*)(&As[k][tr * 4]);
      float4 bv = *(const float4*)(&Bs[k][tc * 4]);
      acc[0][0] = fmaf(av.x, bv.x, acc[0][0]); acc[0][1] = fmaf(av.x, bv.y, acc[0][1]);
      acc[0][2] = fmaf(av.x, bv.z, acc[0][2]); acc[0][3] = fmaf(av.x, bv.w, acc[0][3]);
      acc[1][0] = fmaf(av.y, bv.x, acc[1][0]); acc[1][1] = fmaf(av.y, bv.y, acc[1][1]);
      acc[1][2] = fmaf(av.y, bv.z, acc[1][2]); acc[1][3] = fmaf(av.y, bv.w, acc[1][3]);
      acc[2][0] = fmaf(av.z, bv.x, acc[2][0]); acc[2][1] = fmaf(av.z, bv.y, acc[2][1]);
      acc[2][2] = fmaf(av.z, bv.z, acc[2][2]); acc[2][3] = fmaf(av.z, bv.w, acc[2][3]);
      acc[3][0] = fmaf(av.w, bv.x, acc[3][0]); acc[3][1] = fmaf(av.w, bv.y, acc[3][1]);
      acc[3][2] = fmaf(av.w, bv.z, acc[3][2]); acc[3][3] = fmaf(av.w, bv.w, acc[3][3]);
    }
    __syncthreads();
  }
#pragma unroll
  for (int i = 0; i < 4; ++i) {
    int row = rbase + tr * 4 + i;
    if (row < 2000) {
#pragma unroll
      for (int j = 0; j < 4; ++j) {
        int o = obase + tc * 4 + j;
        float v = acc[i][j] + bias[o];
        if (row < 1600) {
          det[(size_t)row * 256 + o] = v + det_q[(row % 100) * 256 + o];
        } else {
          int t2 = row - 1600;
          rec[(size_t)t2 * 256 + o] = v + rec_q[(t2 % 25) * 256 + o];
        }
      }
    }
  }
}

extern "C" void kernel_launch(void* const* d_in, const int* in_sizes, int n_in,
                              void* d_out, int out_size, void* d_ws, size_t ws_size,
                              hipStream_t stream) {
  const float* x     = (const float*)d_in[0];
  const float* Wc    = (const float*)d_in[1];
  const float* bc    = (const float*)d_in[2];
  const float* Wb    = (const float*)d_in[3];
  const float* bb    = (const float*)d_in[4];
  const float* dW1   = (const float*)d_in[5];
  const float* db1   = (const float*)d_in[6];
  const float* dW2   = (const float*)d_in[7];
  const float* db2   = (const float*)d_in[8];
  const float* dW3   = (const float*)d_in[9];
  const float* db3   = (const float*)d_in[10];
  const float* rW1   = (const float*)d_in[11];
  const float* rb1   = (const float*)d_in[12];
  const float* rW2   = (const float*)d_in[13];
  const float* rb2   = (const float*)d_in[14];
  const float* rW3   = (const float*)d_in[15];
  const float* rb3   = (const float*)d_in[16];
  const float* det_q = (const float*)d_in[17];
  const float* rec_q = (const float*)d_in[18];
  const float* pos_e = (const float*)d_in[19];

  float* out  = (float*)d_out;
  float* det  = out;                // [16,100,256]
  float* rec  = out + 409600;       // [16, 25,256]
  float* cls  = out + 512000;       // [16,10000,2]
  float* bbox = out + 832000;       // [16,10000,4]

  // ws (bytes): wT @0 (1572864) | conf @1572864 (640000) | idx @2212864 (8192)
  //             wpe @2221056 (60000) | actA @2281056 (2048*1024) | actB @4378208 (2048*1024)
  char* wsb = (char*)d_ws;
  float* wT   = (float*)wsb;
  float* conf = (float*)(wsb + 1572864);
  int*   idx  = (int*)(wsb + 2212864);
  float* wpe  = (float*)(wsb + 2221056);
  float* actA = (float*)(wsb + 2281056);
  float* actB = (float*)(wsb + 4378208);

  const float* wTd1 = wT;
  const float* wTd2 = wT + 65536;
  const float* wTd3 = wT + 131072;
  const float* wTr1 = wT + 196608;
  const float* wTr2 = wT + 262144;
  const float* wTr3 = wT + 327680;

  k_prep<<<156, 256, 0, stream>>>(pos_e, Wc, Wb, dW1, dW2, dW3, rW1, rW2, rW3, wpe, wT);
  k_heads4<<<dim3(40, B_SZ), 256, 0, stream>>>(x, wpe, Wc, bc, Wb, bb, cls, bbox, conf);
  k_topk<<<B_SZ, 1024, 0, stream>>>(conf, idx);
  k_gather<<<250, 256, 0, stream>>>(x, pos_e, idx, actA);
  k_lin<<<dim3(32, 4), 256, 0, stream>>>(actA, actB, wTd1, wTr1, db1, rb1);
  k_lin<<<dim3(32, 4), 256, 0, stream>>>(actB, actA, wTd2, wTr2, db2, rb2);
  k_lin3<<<dim3(32, 4), 256, 0, stream>>>(actA, wTd3, wTr3, db3, rb3,
                                          det_q, rec_q, det, rec);
}

// Round 14
// 113.185 us; speedup vs baseline: 2.9370x; 1.2821x over previous
//
#include <hip/hip_runtime.h>
#include <cstdint>
#include <cstddef>

#define C_DIM 256
#define N_PIX 10000
#define B_SZ 16

// ---------------- k_prep (R10-exact): wpe (0..59) + tiled weight transpose (60..155) ----
__global__ __launch_bounds__(256) void k_prep(
    const float* __restrict__ pe,
    const float* __restrict__ Wc, const float* __restrict__ Wb,
    const float* __restrict__ dW1, const float* __restrict__ dW2, const float* __restrict__ dW3,
    const float* __restrict__ rW1, const float* __restrict__ rW2, const float* __restrict__ rW3,
    float* __restrict__ wpe, float* __restrict__ wT) {
  __shared__ float tile[64][65];
  int tid = threadIdx.x;
  int bid = blockIdx.x;
  if (bid < 60) {
    int o = bid / 10;
    int p = (bid % 10) * 256 + tid;
    if (p >= 2500) return;
    const float* W = (o < 2) ? (Wc + o * C_DIM) : (Wb + (o - 2) * C_DIM);
    float acc = 0.f;
#pragma unroll 8
    for (int c = 0; c < C_DIM; ++c) acc = fmaf(W[c], pe[c * 2500 + p], acc);
    wpe[o * 2500 + p] = acc;
    return;
  }
  int t = bid - 60;
  int m = t >> 4;
  int tl = t & 15;
  int ty = tl >> 2, tx = tl & 3;
  const float* W;
  switch (m) {
    case 0: W = dW1; break;
    case 1: W = dW2; break;
    case 2: W = dW3; break;
    case 3: W = rW1; break;
    case 4: W = rW2; break;
    default: W = rW3; break;
  }
  int lane = tid & 63, rg = tid >> 6;
  for (int rr = rg; rr < 64; rr += 4)
    tile[rr][lane] = W[(size_t)(ty * 64 + rr) * 256 + tx * 64 + lane];
  __syncthreads();
  for (int rr = rg; rr < 64; rr += 4)
    wT[(size_t)m * 65536 + (size_t)(tx * 64 + rr) * 256 + ty * 64 + lane] = tile[lane][rr];
}

// ---------------- k_heads4 (R12-exact) --------------------------------------------------
__global__ __launch_bounds__(256, 4) void k_heads4(
    const float* __restrict__ x, const float* __restrict__ wpe,
    const float* __restrict__ Wc, const float* __restrict__ bc,
    const float* __restrict__ Wb, const float* __restrict__ bb,
    float* __restrict__ cls, float* __restrict__ bbox, float* __restrict__ conf) {
  int tid = threadIdx.x;
  int b = blockIdx.y;
  int n = blockIdx.x * 256 + tid;
  if (n >= N_PIX) return;
  const float* xb = x + (size_t)b * C_DIM * N_PIX + n;
  const float* w1p = Wc + C_DIM;
  const float* w2p = Wb;
  const float* w3p = Wb + C_DIM;
  const float* w4p = Wb + 2 * C_DIM;
  const float* w5p = Wb + 3 * C_DIM;
  float a0 = 0.f, a1 = 0.f, a2 = 0.f, a3 = 0.f, a4 = 0.f, a5 = 0.f;
  for (int c = 0; c < C_DIM; c += 16) {
    float xv[16];
#pragma unroll
    for (int j = 0; j < 16; ++j) xv[j] = xb[(size_t)(c + j) * N_PIX];
#pragma unroll
    for (int j = 0; j < 16; ++j) {
      float v = xv[j];
      a0 = fmaf(Wc[c + j],  v, a0);
      a1 = fmaf(w1p[c + j], v, a1);
      a2 = fmaf(w2p[c + j], v, a2);
      a3 = fmaf(w3p[c + j], v, a3);
      a4 = fmaf(w4p[c + j], v, a4);
      a5 = fmaf(w5p[c + j], v, a5);
    }
  }
  int y = n / 100, xq = n % 100;
  float sy = fminf(fmaxf((y + 0.5f) * 0.5f - 0.5f, 0.0f), 49.0f);
  float sx = fminf(fmaxf((xq + 0.5f) * 0.5f - 0.5f, 0.0f), 49.0f);
  int y0 = (int)floorf(sy); int y1 = min(y0 + 1, 49); float ty = sy - (float)y0;
  int x0i = (int)floorf(sx); int x1i = min(x0i + 1, 49); float tx = sx - (float)x0i;
  float pd[6];
#pragma unroll
  for (int o = 0; o < 6; ++o) {
    const float* m = wpe + o * 2500;
    float v00 = m[y0 * 50 + x0i], v01 = m[y0 * 50 + x1i];
    float v10 = m[y1 * 50 + x0i], v11 = m[y1 * 50 + x1i];
    float r0 = v00 * (1.0f - ty) + v10 * ty;
    float r1 = v01 * (1.0f - ty) + v11 * ty;
    pd[o] = r0 * (1.0f - tx) + r1 * tx;
  }
  float c0 = a0 + pd[0] + bc[0];
  float c1 = a1 + pd[1] + bc[1];
  float b0 = a2 + pd[2] + bb[0];
  float b1 = a3 + pd[3] + bb[1];
  float b2 = a4 + pd[4] + bb[2];
  float b3 = a5 + pd[5] + bb[3];
  size_t nb = (size_t)b * N_PIX + n;
  float2 cv; cv.x = c0; cv.y = c1;
  *(float2*)(cls + nb * 2) = cv;
  float4 bv; bv.x = b0; bv.y = b1; bv.z = b2; bv.w = b3;
  *(float4*)(bbox + nb * 4) = bv;
  float m0 = fmaxf(c0, c1);
  float e0 = expf(c0 - m0), e1 = expf(c1 - m0);
  conf[nb] = e1 / (e0 + e1);
}

// ---------------- k_topk: log-tree suffix scan (R13 selection semantics) ----------------
__global__ __launch_bounds__(1024) void k_topk(const float* __restrict__ conf,
                                               int* __restrict__ idx_out) {
  __shared__ unsigned int ord[N_PIX];
  __shared__ unsigned int whist[16][256];
  __shared__ unsigned int sfx[256];
  __shared__ unsigned long long cand[512];
  __shared__ unsigned int s_cnt, s_prefix, s_ncand;
  int tid = threadIdx.x;
  int wv = tid >> 6;
  int b = blockIdx.x;
  const float* cb = conf + (size_t)b * N_PIX;
  for (int i = tid; i < N_PIX; i += 1024) {
    unsigned int u = __float_as_uint(cb[i]);
    ord[i] = (u & 0x80000000u) ? ~u : (u | 0x80000000u);
  }
  unsigned int prefix = 0, cnt_gt = 0;
  for (int pass = 0; pass < 4; ++pass) {
    int sh = 24 - 8 * pass;
    for (int i = tid; i < 16 * 256; i += 1024) ((unsigned int*)whist)[i] = 0;
    __syncthreads();
    unsigned int himask = (pass == 0) ? 0u : (0xFFFFFFFFu << (sh + 8));
    for (int i = tid; i < N_PIX; i += 1024) {
      unsigned int o = ord[i];
      if ((o & himask) == prefix) atomicAdd(&whist[wv][(o >> sh) & 255u], 1u);
    }
    __syncthreads();
    // sfx[t] starts as hist[t] (reduced over 16 wave-rows), then log-tree suffix scan
    if (tid < 256) {
      unsigned int s = 0;
#pragma unroll
      for (int w2 = 0; w2 < 16; ++w2) s += whist[w2][tid];
      sfx[tid] = s;
    }
    __syncthreads();
#pragma unroll
    for (int off = 1; off < 256; off <<= 1) {
      unsigned int add = 0;
      if (tid < 256 && tid + off < 256) add = sfx[tid + off];
      __syncthreads();
      if (tid < 256) sfx[tid] += add;
      __syncthreads();
    }
    // v* = max{v : cnt_gt + sfx[v] >= 100}; new cnt = cnt_gt + sfx[v*+1]
    if (tid < 256) {
      unsigned int Sv = sfx[tid];
      unsigned int Sn = (tid < 255) ? sfx[tid + 1] : 0u;
      if (cnt_gt + Sv >= 100u && (tid == 255 || cnt_gt + Sn < 100u)) {
        s_cnt = cnt_gt + Sn;
        s_prefix = prefix | ((unsigned int)tid << sh);
      }
    }
    __syncthreads();
    cnt_gt = s_cnt; prefix = s_prefix;
    __syncthreads();
  }
  if (tid == 0) s_ncand = 0;
  __syncthreads();
  unsigned int T = prefix;
  for (int i = tid; i < N_PIX; i += 1024) {
    unsigned int o = ord[i];
    if (o >= T) {
      unsigned int k = atomicAdd(&s_ncand, 1u);
      if (k < 512u)
        cand[k] = ((unsigned long long)o << 32) |
                  (unsigned long long)(0xFFFFFFFFu - (unsigned int)i);
    }
  }
  __syncthreads();
  unsigned int nc = s_ncand > 512u ? 512u : s_ncand;
  for (int i = tid; i < 512; i += 1024)
    if ((unsigned int)i >= nc) cand[i] = 0ull;
  __syncthreads();
  for (unsigned int k = 2; k <= 512; k <<= 1) {
    for (unsigned int j = k >> 1; j > 0; j >>= 1) {
      if (tid < 512) {
        unsigned int i = (unsigned int)tid, ixj = i ^ j;
        if (ixj > i) {
          unsigned long long a = cand[i], c2 = cand[ixj];
          bool up = ((i & k) == 0);
          if ((a > c2) == up) { cand[i] = c2; cand[ixj] = a; }
        }
      }
      __syncthreads();
    }
  }
  if (tid < 100) {
    unsigned long long key = cand[511 - tid];
    idx_out[b * 100 + tid] = (int)(0xFFFFFFFFu - (unsigned int)(key & 0xFFFFFFFFull));
  }
}

// ---------------- k_mlp5 (R10-exact) ----------------------------------------------------
#define R4 4

__device__ __forceinline__ float pos_bilinear(const float* __restrict__ pe, int c, int n) {
  int y = n / 100, xq = n % 100;
  float sy = fminf(fmaxf((y + 0.5f) * 0.5f - 0.5f, 0.0f), 49.0f);
  float sx = fminf(fmaxf((xq + 0.5f) * 0.5f - 0.5f, 0.0f), 49.0f);
  int y0 = (int)floorf(sy); int y1 = min(y0 + 1, 49); float ty = sy - (float)y0;
  int x0i = (int)floorf(sx); int x1i = min(x0i + 1, 49); float tx = sx - (float)x0i;
  const float* p = pe + (size_t)c * 2500;
  float v00 = p[y0 * 50 + x0i], v01 = p[y0 * 50 + x1i];
  float v10 = p[y1 * 50 + x0i], v11 = p[y1 * 50 + x1i];
  float rr0 = v00 * (1.0f - ty) + v10 * ty;
  float rr1 = v01 * (1.0f - ty) + v11 * ty;
  return rr0 * (1.0f - tx) + rr1 * tx;
}

__device__ __forceinline__ void mlp_layer_cs(const float (*in)[C_DIM], float (*outb)[C_DIM],
    float (*red)[R4][C_DIM], const float* __restrict__ Wl, const float* __restrict__ bias,
    bool relu, int og, int rg, int tid) {
  float4 acc[R4];
#pragma unroll
  for (int r = 0; r < R4; ++r) { acc[r].x = 0.f; acc[r].y = 0.f; acc[r].z = 0.f; acc[r].w = 0.f; }
  int c0 = rg * 64;
#pragma unroll 4
  for (int ci = 0; ci < 64; ci += 4) {
    int c = c0 + ci;
    float4 w0 = *(const float4*)(Wl + (size_t)(c + 0) * C_DIM + og * 4);
    float4 w1 = *(const float4*)(Wl + (size_t)(c + 1) * C_DIM + og * 4);
    float4 w2 = *(const float4*)(Wl + (size_t)(c + 2) * C_DIM + og * 4);
    float4 w3 = *(const float4*)(Wl + (size_t)(c + 3) * C_DIM + og * 4);
#pragma unroll
    for (int r = 0; r < R4; ++r) {
      float4 iv = *(const float4*)(&in[r][c]);
      acc[r].x = fmaf(w0.x, iv.x, acc[r].x); acc[r].y = fmaf(w0.y, iv.x, acc[r].y);
      acc[r].z = fmaf(w0.z, iv.x, acc[r].z); acc[r].w = fmaf(w0.w, iv.x, acc[r].w);
      acc[r].x = fmaf(w1.x, iv.y, acc[r].x); acc[r].y = fmaf(w1.y, iv.y, acc[r].y);
      acc[r].z = fmaf(w1.z, iv.y, acc[r].z); acc[r].w = fmaf(w1.w, iv.y, acc[r].w);
      acc[r].x = fmaf(w2.x, iv.z, acc[r].x); acc[r].y = fmaf(w2.y, iv.z, acc[r].y);
      acc[r].z = fmaf(w2.z, iv.z, acc[r].z); acc[r].w = fmaf(w2.w, iv.z, acc[r].w);
      acc[r].x = fmaf(w3.x, iv.w, acc[r].x); acc[r].y = fmaf(w3.y, iv.w, acc[r].y);
      acc[r].z = fmaf(w3.z, iv.w, acc[r].z); acc[r].w = fmaf(w3.w, iv.w, acc[r].w);
    }
  }
#pragma unroll
  for (int r = 0; r < R4; ++r) *(float4*)(&red[rg][r][og * 4]) = acc[r];
  __syncthreads();
#pragma unroll
  for (int r = 0; r < R4; ++r) {
    float s = red[0][r][tid] + red[1][r][tid] + red[2][r][tid] + red[3][r][tid] + bias[tid];
    outb[r][tid] = relu ? fmaxf(s, 0.f) : s;
  }
  __syncthreads();
}

__global__ __launch_bounds__(256, 2) void k_mlp5(
    const float* __restrict__ x, const float* __restrict__ pe, const int* __restrict__ idx,
    const float* __restrict__ wT,
    const float* __restrict__ db1, const float* __restrict__ db2, const float* __restrict__ db3,
    const float* __restrict__ rb1, const float* __restrict__ rb2, const float* __restrict__ rb3,
    const float* __restrict__ det_q, const float* __restrict__ rec_q,
    float* __restrict__ det, float* __restrict__ rec) {
  __shared__ float actA[R4][C_DIM];
  __shared__ float actB[R4][C_DIM];
  __shared__ float red[4][R4][C_DIM];
  int tid = threadIdx.x;
  int og = tid & 63, rg = tid >> 6;
  int base = blockIdx.x * R4;
  bool is_det = base < 1600;
  const float *W1, *W2, *W3, *B1, *B2, *B3;
  if (is_det) {
    W1 = wT;          W2 = wT + 65536;  W3 = wT + 131072;
    B1 = db1; B2 = db2; B3 = db3;
  } else {
    W1 = wT + 196608; W2 = wT + 262144; W3 = wT + 327680;
    B1 = rb1; B2 = rb2; B3 = rb3;
  }
#pragma unroll
  for (int lr = 0; lr < R4; ++lr) {
    int rowid = base + lr;
    int b, r;
    if (rowid < 1600) { b = rowid / 100; r = rowid % 100; }
    else { int t2 = rowid - 1600; b = t2 / 25; r = t2 % 25; }
    int n = idx[b * 100 + r];
    actA[lr][tid] = x[((size_t)b * C_DIM + tid) * N_PIX + n] + pos_bilinear(pe, tid, n);
  }
  __syncthreads();
  mlp_layer_cs(actA, actB, red, W1, B1, true,  og, rg, tid);
  mlp_layer_cs(actB, actA, red, W2, B2, true,  og, rg, tid);
  mlp_layer_cs(actA, actB, red, W3, B3, false, og, rg, tid);
#pragma unroll
  for (int lr = 0; lr < R4; ++lr) {
    int rowid = base + lr;
    if (rowid < 1600) {
      int r = rowid % 100;
      det[(size_t)rowid * C_DIM + tid] = actB[lr][tid] + det_q[r * C_DIM + tid];
    } else {
      int t2 = rowid - 1600; int r = t2 % 25;
      rec[(size_t)t2 * C_DIM + tid] = actB[lr][tid] + rec_q[r * C_DIM + tid];
    }
  }
}

extern "C" void kernel_launch(void* const* d_in, const int* in_sizes, int n_in,
                              void* d_out, int out_size, void* d_ws, size_t ws_size,
                              hipStream_t stream) {
  const float* x     = (const float*)d_in[0];
  const float* Wc    = (const float*)d_in[1];
  const float* bc    = (const float*)d_in[2];
  const float* Wb    = (const float*)d_in[3];
  const float* bb    = (const float*)d_in[4];
  const float* dW1   = (const float*)d_in[5];
  const float* db1   = (const float*)d_in[6];
  const float* dW2   = (const float*)d_in[7];
  const float* db2   = (const float*)d_in[8];
  const float* dW3   = (const float*)d_in[9];
  const float* db3   = (const float*)d_in[10];
  const float* rW1   = (const float*)d_in[11];
  const float* rb1   = (const float*)d_in[12];
  const float* rW2   = (const float*)d_in[13];
  const float* rb2   = (const float*)d_in[14];
  const float* rW3   = (const float*)d_in[15];
  const float* rb3   = (const float*)d_in[16];
  const float* det_q = (const float*)d_in[17];
  const float* rec_q = (const float*)d_in[18];
  const float* pos_e = (const float*)d_in[19];

  float* out  = (float*)d_out;
  float* det  = out;                // [16,100,256]
  float* rec  = out + 409600;       // [16, 25,256]
  float* cls  = out + 512000;       // [16,10000,2]
  float* bbox = out + 832000;       // [16,10000,4]

  // ws layout (bytes): wT @0 (1572864) | conf @1572864 (640000) | idx @2212864 | wpe @2221056
  char* wsb = (char*)d_ws;
  float* wT   = (float*)wsb;
  float* conf = (float*)(wsb + 1572864);
  int*   idx  = (int*)(wsb + 2212864);
  float* wpe  = (float*)(wsb + 2221056);

  k_prep<<<156, 256, 0, stream>>>(pos_e, Wc, Wb, dW1, dW2, dW3, rW1, rW2, rW3, wpe, wT);
  k_heads4<<<dim3(40, B_SZ), 256, 0, stream>>>(x, wpe, Wc, bc, Wb, bb, cls, bbox, conf);
  k_topk<<<B_SZ, 1024, 0, stream>>>(conf, idx);
  k_mlp5<<<500, 256, 0, stream>>>(x, pos_e, idx, wT,
                                  db1, db2, db3, rb1, rb2, rb3,
                                  det_q, rec_q, det, rec);
}

// Round 15
// 106.802 us; speedup vs baseline: 3.1125x; 1.0598x over previous
//
#include <hip/hip_runtime.h>
#include <cstdint>
#include <cstddef>

#define C_DIM 256
#define N_PIX 10000
#define B_SZ 16

// ---------------- k_prep_wpe: wpe[o][p] = sum_c W[o][c] * pe[c][p] ----------------------
__global__ __launch_bounds__(256) void k_prep_wpe(
    const float* __restrict__ pe,
    const float* __restrict__ Wc, const float* __restrict__ Wb,
    float* __restrict__ wpe) {
  int tid = threadIdx.x;
  int bid = blockIdx.x;                 // 60 blocks
  int o = bid / 10;
  int p = (bid % 10) * 256 + tid;
  if (p >= 2500) return;
  const float* W = (o < 2) ? (Wc + o * C_DIM) : (Wb + (o - 2) * C_DIM);
  float acc = 0.f;
#pragma unroll 8
  for (int c = 0; c < C_DIM; ++c) acc = fmaf(W[c], pe[c * 2500 + p], acc);
  wpe[o * 2500 + p] = acc;
}

// ---------------- k_heads4 (R14-exact) --------------------------------------------------
__global__ __launch_bounds__(256, 4) void k_heads4(
    const float* __restrict__ x, const float* __restrict__ wpe,
    const float* __restrict__ Wc, const float* __restrict__ bc,
    const float* __restrict__ Wb, const float* __restrict__ bb,
    float* __restrict__ cls, float* __restrict__ bbox, float* __restrict__ conf) {
  int tid = threadIdx.x;
  int b = blockIdx.y;
  int n = blockIdx.x * 256 + tid;
  if (n >= N_PIX) return;
  const float* xb = x + (size_t)b * C_DIM * N_PIX + n;
  const float* w1p = Wc + C_DIM;
  const float* w2p = Wb;
  const float* w3p = Wb + C_DIM;
  const float* w4p = Wb + 2 * C_DIM;
  const float* w5p = Wb + 3 * C_DIM;
  float a0 = 0.f, a1 = 0.f, a2 = 0.f, a3 = 0.f, a4 = 0.f, a5 = 0.f;
  for (int c = 0; c < C_DIM; c += 16) {
    float xv[16];
#pragma unroll
    for (int j = 0; j < 16; ++j) xv[j] = xb[(size_t)(c + j) * N_PIX];
#pragma unroll
    for (int j = 0; j < 16; ++j) {
      float v = xv[j];
      a0 = fmaf(Wc[c + j],  v, a0);
      a1 = fmaf(w1p[c + j], v, a1);
      a2 = fmaf(w2p[c + j], v, a2);
      a3 = fmaf(w3p[c + j], v, a3);
      a4 = fmaf(w4p[c + j], v, a4);
      a5 = fmaf(w5p[c + j], v, a5);
    }
  }
  int y = n / 100, xq = n % 100;
  float sy = fminf(fmaxf((y + 0.5f) * 0.5f - 0.5f, 0.0f), 49.0f);
  float sx = fminf(fmaxf((xq + 0.5f) * 0.5f - 0.5f, 0.0f), 49.0f);
  int y0 = (int)floorf(sy); int y1 = min(y0 + 1, 49); float ty = sy - (float)y0;
  int x0i = (int)floorf(sx); int x1i = min(x0i + 1, 49); float tx = sx - (float)x0i;
  float pd[6];
#pragma unroll
  for (int o = 0; o < 6; ++o) {
    const float* m = wpe + o * 2500;
    float v00 = m[y0 * 50 + x0i], v01 = m[y0 * 50 + x1i];
    float v10 = m[y1 * 50 + x0i], v11 = m[y1 * 50 + x1i];
    float r0 = v00 * (1.0f - ty) + v10 * ty;
    float r1 = v01 * (1.0f - ty) + v11 * ty;
    pd[o] = r0 * (1.0f - tx) + r1 * tx;
  }
  float c0 = a0 + pd[0] + bc[0];
  float c1 = a1 + pd[1] + bc[1];
  float b0 = a2 + pd[2] + bb[0];
  float b1 = a3 + pd[3] + bb[1];
  float b2 = a4 + pd[4] + bb[2];
  float b3 = a5 + pd[5] + bb[3];
  size_t nb = (size_t)b * N_PIX + n;
  float2 cv; cv.x = c0; cv.y = c1;
  *(float2*)(cls + nb * 2) = cv;
  float4 bv; bv.x = b0; bv.y = b1; bv.z = b2; bv.w = b3;
  *(float4*)(bbox + nb * 4) = bv;
  float m0 = fmaxf(c0, c1);
  float e0 = expf(c0 - m0), e1 = expf(c1 - m0);
  conf[nb] = e1 / (e0 + e1);
}

// ---------------- k_topk_plus: blocks 0..15 top-k (R14-exact body) ----------------------
//                  blocks 16..111: wT transpose (overlaps; wT used only by k_mlp6)
__global__ __launch_bounds__(1024) void k_topk_plus(
    const float* __restrict__ conf, int* __restrict__ idx_out,
    const float* __restrict__ dW1, const float* __restrict__ dW2, const float* __restrict__ dW3,
    const float* __restrict__ rW1, const float* __restrict__ rW2, const float* __restrict__ rW3,
    float* __restrict__ wT) {
  int tid = threadIdx.x;
  int bid = blockIdx.x;
  if (bid >= 16) {
    __shared__ float tile[64][65];
    int t = bid - 16;                 // 96 blocks: 6 matrices x 16 (64x64) tiles
    int m = t >> 4;
    int tl = t & 15;
    int ty = tl >> 2, tx = tl & 3;
    const float* W;
    switch (m) {
      case 0: W = dW1; break;
      case 1: W = dW2; break;
      case 2: W = dW3; break;
      case 3: W = rW1; break;
      case 4: W = rW2; break;
      default: W = rW3; break;
    }
    int lane = tid & 63, rg = tid >> 6;       // 16 row-groups
    for (int rr = rg; rr < 64; rr += 16)
      tile[rr][lane] = W[(size_t)(ty * 64 + rr) * 256 + tx * 64 + lane];
    __syncthreads();
    for (int rr = rg; rr < 64; rr += 16)
      wT[(size_t)m * 65536 + (size_t)(tx * 64 + rr) * 256 + ty * 64 + lane] = tile[lane][rr];
    return;
  }
  __shared__ unsigned int ord[N_PIX];
  __shared__ unsigned int whist[16][256];
  __shared__ unsigned int sfx[256];
  __shared__ unsigned long long cand[512];
  __shared__ unsigned int s_cnt, s_prefix, s_ncand;
  int wv = tid >> 6;
  int b = bid;
  const float* cb = conf + (size_t)b * N_PIX;
  for (int i = tid; i < N_PIX; i += 1024) {
    unsigned int u = __float_as_uint(cb[i]);
    ord[i] = (u & 0x80000000u) ? ~u : (u | 0x80000000u);
  }
  unsigned int prefix = 0, cnt_gt = 0;
  for (int pass = 0; pass < 4; ++pass) {
    int sh = 24 - 8 * pass;
    for (int i = tid; i < 16 * 256; i += 1024) ((unsigned int*)whist)[i] = 0;
    __syncthreads();
    unsigned int himask = (pass == 0) ? 0u : (0xFFFFFFFFu << (sh + 8));
    for (int i = tid; i < N_PIX; i += 1024) {
      unsigned int o = ord[i];
      if ((o & himask) == prefix) atomicAdd(&whist[wv][(o >> sh) & 255u], 1u);
    }
    __syncthreads();
    if (tid < 256) {
      unsigned int s = 0;
#pragma unroll
      for (int w2 = 0; w2 < 16; ++w2) s += whist[w2][tid];
      sfx[tid] = s;
    }
    __syncthreads();
#pragma unroll
    for (int off = 1; off < 256; off <<= 1) {
      unsigned int add = 0;
      if (tid < 256 && tid + off < 256) add = sfx[tid + off];
      __syncthreads();
      if (tid < 256) sfx[tid] += add;
      __syncthreads();
    }
    if (tid < 256) {
      unsigned int Sv = sfx[tid];
      unsigned int Sn = (tid < 255) ? sfx[tid + 1] : 0u;
      if (cnt_gt + Sv >= 100u && (tid == 255 || cnt_gt + Sn < 100u)) {
        s_cnt = cnt_gt + Sn;
        s_prefix = prefix | ((unsigned int)tid << sh);
      }
    }
    __syncthreads();
    cnt_gt = s_cnt; prefix = s_prefix;
    __syncthreads();
  }
  if (tid == 0) s_ncand = 0;
  __syncthreads();
  unsigned int T = prefix;
  for (int i = tid; i < N_PIX; i += 1024) {
    unsigned int o = ord[i];
    if (o >= T) {
      unsigned int k = atomicAdd(&s_ncand, 1u);
      if (k < 512u)
        cand[k] = ((unsigned long long)o << 32) |
                  (unsigned long long)(0xFFFFFFFFu - (unsigned int)i);
    }
  }
  __syncthreads();
  unsigned int nc = s_ncand > 512u ? 512u : s_ncand;
  for (int i = tid; i < 512; i += 1024)
    if ((unsigned int)i >= nc) cand[i] = 0ull;
  __syncthreads();
  for (unsigned int k = 2; k <= 512; k <<= 1) {
    for (unsigned int j = k >> 1; j > 0; j >>= 1) {
      if (tid < 512) {
        unsigned int i = (unsigned int)tid, ixj = i ^ j;
        if (ixj > i) {
          unsigned long long a = cand[i], c2 = cand[ixj];
          bool up = ((i & k) == 0);
          if ((a > c2) == up) { cand[i] = c2; cand[ixj] = a; }
        }
      }
      __syncthreads();
    }
  }
  if (tid < 100) {
    unsigned long long key = cand[511 - tid];
    idx_out[b * 100 + tid] = (int)(0xFFFFFFFFu - (unsigned int)(key & 0xFFFFFFFFull));
  }
}

// ---------------- k_mlp6: 512 thr, R=8 rows/block (250 blocks), c-split 8 waves ----------
// Halves weight L2 traffic vs mlp5 (192MB) and doubles waves/CU (16). LDS exactly 80KB.
#define R8 8

__device__ __forceinline__ float pos_bilinear(const float* __restrict__ pe, int c, int n) {
  int y = n / 100, xq = n % 100;
  float sy = fminf(fmaxf((y + 0.5f) * 0.5f - 0.5f, 0.0f), 49.0f);
  float sx = fminf(fmaxf((xq + 0.5f) * 0.5f - 0.5f, 0.0f), 49.0f);
  int y0 = (int)floorf(sy); int y1 = min(y0 + 1, 49); float ty = sy - (float)y0;
  int x0i = (int)floorf(sx); int x1i = min(x0i + 1, 49); float tx = sx - (float)x0i;
  const float* p = pe + (size_t)c * 2500;
  float v00 = p[y0 * 50 + x0i], v01 = p[y0 * 50 + x1i];
  float v10 = p[y1 * 50 + x0i], v11 = p[y1 * 50 + x1i];
  float rr0 = v00 * (1.0f - ty) + v10 * ty;
  float rr1 = v01 * (1.0f - ty) + v11 * ty;
  return rr0 * (1.0f - tx) + rr1 * tx;
}

__device__ __forceinline__ void mlp6_layer(const float (*in)[C_DIM], float (*outb)[C_DIM],
    float (*red)[R8][C_DIM], const float* __restrict__ Wl, const float* __restrict__ bias,
    bool relu, int og, int rg, int tid) {
  float4 acc[R8];
#pragma unroll
  for (int r = 0; r < R8; ++r) { acc[r].x = 0.f; acc[r].y = 0.f; acc[r].z = 0.f; acc[r].w = 0.f; }
  int c0 = rg * 32;                     // each of 8 waves owns 32 channels
#pragma unroll 2
  for (int ci = 0; ci < 32; ci += 4) {
    int c = c0 + ci;
    float4 w0 = *(const float4*)(Wl + (size_t)(c + 0) * C_DIM + og * 4);
    float4 w1 = *(const float4*)(Wl + (size_t)(c + 1) * C_DIM + og * 4);
    float4 w2 = *(const float4*)(Wl + (size_t)(c + 2) * C_DIM + og * 4);
    float4 w3 = *(const float4*)(Wl + (size_t)(c + 3) * C_DIM + og * 4);
#pragma unroll
    for (int r = 0; r < R8; ++r) {
      float4 iv = *(const float4*)(&in[r][c]);
      acc[r].x = fmaf(w0.x, iv.x, acc[r].x); acc[r].y = fmaf(w0.y, iv.x, acc[r].y);
      acc[r].z = fmaf(w0.z, iv.x, acc[r].z); acc[r].w = fmaf(w0.w, iv.x, acc[r].w);
      acc[r].x = fmaf(w1.x, iv.y, acc[r].x); acc[r].y = fmaf(w1.y, iv.y, acc[r].y);
      acc[r].z = fmaf(w1.z, iv.y, acc[r].z); acc[r].w = fmaf(w1.w, iv.y, acc[r].w);
      acc[r].x = fmaf(w2.x, iv.z, acc[r].x); acc[r].y = fmaf(w2.y, iv.z, acc[r].y);
      acc[r].z = fmaf(w2.z, iv.z, acc[r].z); acc[r].w = fmaf(w2.w, iv.z, acc[r].w);
      acc[r].x = fmaf(w3.x, iv.w, acc[r].x); acc[r].y = fmaf(w3.y, iv.w, acc[r].y);
      acc[r].z = fmaf(w3.z, iv.w, acc[r].z); acc[r].w = fmaf(w3.w, iv.w, acc[r].w);
    }
  }
#pragma unroll
  for (int r = 0; r < R8; ++r) *(float4*)(&red[rg][r][og * 4]) = acc[r];
  __syncthreads();
  // reduce: 2048 outputs, thread handles 4 (r,o) elements
#pragma unroll
  for (int k = 0; k < 4; ++k) {
    int e = tid + k * 512;
    int r = e >> 8, o = e & 255;
    float s = bias[o];
#pragma unroll
    for (int g = 0; g < 8; ++g) s += red[g][r][o];
    outb[r][o] = relu ? fmaxf(s, 0.f) : s;
  }
  __syncthreads();
}

__global__ __launch_bounds__(512, 2) void k_mlp6(
    const float* __restrict__ x, const float* __restrict__ pe, const int* __restrict__ idx,
    const float* __restrict__ wT,
    const float* __restrict__ db1, const float* __restrict__ db2, const float* __restrict__ db3,
    const float* __restrict__ rb1, const float* __restrict__ rb2, const float* __restrict__ rb3,
    const float* __restrict__ det_q, const float* __restrict__ rec_q,
    float* __restrict__ det, float* __restrict__ rec) {
  __shared__ float actA[R8][C_DIM];
  __shared__ float actB[R8][C_DIM];
  __shared__ float red[8][R8][C_DIM];   // 64KB; total LDS = 80KB -> 2 blocks/CU
  int tid = threadIdx.x;
  int og = tid & 63, rg = tid >> 6;     // og: output quad, rg: wave = c-group
  int base = blockIdx.x * R8;           // 250 blocks; rows 0..1599 det, 1600..1999 rec
  bool is_det = base < 1600;
  const float *W1, *W2, *W3, *B1, *B2, *B3;
  if (is_det) {
    W1 = wT;          W2 = wT + 65536;  W3 = wT + 131072;
    B1 = db1; B2 = db2; B3 = db3;
  } else {
    W1 = wT + 196608; W2 = wT + 262144; W3 = wT + 327680;
    B1 = rb1; B2 = rb2; B3 = rb3;
  }
  // gather: 2048 elements, thread handles 4
#pragma unroll
  for (int k = 0; k < 4; ++k) {
    int e = tid + k * 512;
    int r = e >> 8, c = e & 255;
    int rowid = base + r;
    int b, rr;
    if (rowid < 1600) { b = rowid / 100; rr = rowid % 100; }
    else { int t2 = rowid - 1600; b = t2 / 25; rr = t2 % 25; }
    int n = idx[b * 100 + rr];
    actA[r][c] = x[((size_t)b * C_DIM + c) * N_PIX + n] + pos_bilinear(pe, c, n);
  }
  __syncthreads();
  mlp6_layer(actA, actB, red, W1, B1, true,  og, rg, tid);
  mlp6_layer(actB, actA, red, W2, B2, true,  og, rg, tid);
  mlp6_layer(actA, actB, red, W3, B3, false, og, rg, tid);
#pragma unroll
  for (int k = 0; k < 4; ++k) {
    int e = tid + k * 512;
    int r = e >> 8, o = e & 255;
    int rowid = base + r;
    if (rowid < 1600) {
      int rr = rowid % 100;
      det[(size_t)rowid * C_DIM + o] = actB[r][o] + det_q[rr * C_DIM + o];
    } else {
      int t2 = rowid - 1600; int rr = t2 % 25;
      rec[(size_t)t2 * C_DIM + o] = actB[r][o] + rec_q[rr * C_DIM + o];
    }
  }
}

extern "C" void kernel_launch(void* const* d_in, const int* in_sizes, int n_in,
                              void* d_out, int out_size, void* d_ws, size_t ws_size,
                              hipStream_t stream) {
  const float* x     = (const float*)d_in[0];
  const float* Wc    = (const float*)d_in[1];
  const float* bc    = (const float*)d_in[2];
  const float* Wb    = (const float*)d_in[3];
  const float* bb    = (const float*)d_in[4];
  const float* dW1   = (const float*)d_in[5];
  const float* db1   = (const float*)d_in[6];
  const float* dW2   = (const float*)d_in[7];
  const float* db2   = (const float*)d_in[8];
  const float* dW3   = (const float*)d_in[9];
  const float* db3   = (const float*)d_in[10];
  const float* rW1   = (const float*)d_in[11];
  const float* rb1   = (const float*)d_in[12];
  const float* rW2   = (const float*)d_in[13];
  const float* rb2   = (const float*)d_in[14];
  const float* rW3   = (const float*)d_in[15];
  const float* rb3   = (const float*)d_in[16];
  const float* det_q = (const float*)d_in[17];
  const float* rec_q = (const float*)d_in[18];
  const float* pos_e = (const float*)d_in[19];

  float* out  = (float*)d_out;
  float* det  = out;                // [16,100,256]
  float* rec  = out + 409600;       // [16, 25,256]
  float* cls  = out + 512000;       // [16,10000,2]
  float* bbox = out + 832000;       // [16,10000,4]

  // ws layout (bytes): wT @0 (1572864) | conf @1572864 (640000) | idx @2212864 | wpe @2221056
  char* wsb = (char*)d_ws;
  float* wT   = (float*)wsb;
  float* conf = (float*)(wsb + 1572864);
  int*   idx  = (int*)(wsb + 2212864);
  float* wpe  = (float*)(wsb + 2221056);

  k_prep_wpe<<<60, 256, 0, stream>>>(pos_e, Wc, Wb, wpe);
  k_heads4<<<dim3(40, B_SZ), 256, 0, stream>>>(x, wpe, Wc, bc, Wb, bb, cls, bbox, conf);
  k_topk_plus<<<112, 1024, 0, stream>>>(conf, idx, dW1, dW2, dW3, rW1, rW2, rW3, wT);
  k_mlp6<<<250, 512, 0, stream>>>(x, pos_e, idx, wT,
                                  db1, db2, db3, rb1, rb2, rb3,
                                  det_q, rec_q, det, rec);
}